// Round 15
// baseline (1706.944 us; speedup 1.0000x reference)
//
#include <hip/hip_runtime.h>

#define T_SEQ 543
#define B_TOT 2048

typedef _Float16 f16;
typedef f16   f16x8 __attribute__((ext_vector_type(8)));
typedef float f32x4 __attribute__((ext_vector_type(4)));

#if defined(__has_builtin)
#if __has_builtin(__builtin_amdgcn_rcpf)
#define RCP(x) __builtin_amdgcn_rcpf(x)
#endif
#endif
#ifndef RCP
#define RCP(x) (1.0f / (x))
#endif

__device__ __forceinline__ float sigm(float x)   { return RCP(1.0f + __expf(-x)); }
__device__ __forceinline__ float tanh_f(float x) { return fmaf(-2.0f, RCP(__expf(2.0f * x) + 1.0f), 1.0f); }

__device__ __forceinline__ f32x4 mfma16(f16x8 a, f16x8 b, f32x4 c) {
    return __builtin_amdgcn_mfma_f32_16x16x32_f16(a, b, c, 0, 0, 0);
}

// B-fragment: lane holds w[nrow][k0..k0+8) as f16x8 (row-major fp32 source)
__device__ __forceinline__ f16x8 loadB(const float* __restrict__ g, int nrow, int ldk, int k0) {
    const float* p = g + (size_t)nrow * ldk + k0;
    float4 a = *(const float4*)p;
    float4 b = *(const float4*)(p + 4);
    f16x8 r;
    r[0] = (f16)a.x; r[1] = (f16)a.y; r[2] = (f16)a.z; r[3] = (f16)a.w;
    r[4] = (f16)b.x; r[5] = (f16)b.y; r[6] = (f16)b.z; r[7] = (f16)b.w;
    return r;
}

// ---- LDS layout (bytes). 16 batch rows per block: batch row r -> tile row r.
// ALL state buffers double-buffered (single barrier per iteration).
#define L_H1S 0        // 2 x [16][64]  f16 = 4096  (raw h1)
#define L_H1R 4096     // 2 x [16][64]  f16 = 4096  (relu h1)
#define L_H2S 8192     // 2 x [16][128] f16 = 8192  (raw h2)
#define L_H2R 16384    // 2 x [16][128] f16 = 8192  (relu h2)
#define L_H3S 24576    // 2 x [16][64]  f16 = 4096  (raw h3)
#define L_H3R 28672    // 2 x [16][64]  f16 = 4096  (relu h3)
#define L_X1  32768    // 2 x [16]x16B      = 512   (x staged)
#define L_W1D 33280    // 2 x 8KB           = 16384 (w1 t-slice [64 jo][64 k] f16)
#define SMEM_T 49664

// XOR-swizzled LDS accessors (spread row-strided b128 reads over banks)
__device__ __forceinline__ f16x8 ldsA(const unsigned char* sm, int base, int stride, int row, int kByte) {
    int off = (base + row * stride + kByte) ^ ((row & 7) << 4);
    return *(const f16x8*)(sm + off);
}
__device__ __forceinline__ void stH(unsigned char* sm, int base, int stride, int row, int col, f16 v) {
    int off = (base + row * stride + col * 2) ^ ((row & 7) << 4);
    *(f16*)(sm + off) = v;
}

__global__ void cvt_f16(const float* __restrict__ s, f16* __restrict__ d, int n) {
    int i = blockIdx.x * 256 + threadIdx.x;
    if (i < n) d[i] = (f16)s[i];
}

__device__ __forceinline__ float gru_cell(float aR, float aZ, float aXn, float aHn, float hprev) {
    float r = sigm(aR);
    float z = sigm(aZ);
    float n = tanh_f(aXn + r * aHn);
    return fmaf(z, hprev - n, n);
}

template<bool W1H>
__global__ __launch_bounds__(512, 2) void gru_fused(
    const float* __restrict__ x,
    const float* __restrict__ w_ih1, const float* __restrict__ w_hh1,
    const float* __restrict__ b_ih1, const float* __restrict__ b_hh1,
    const float* __restrict__ w_ih2, const float* __restrict__ w_hh2,
    const float* __restrict__ b_ih2, const float* __restrict__ b_hh2,
    const float* __restrict__ w_ih3, const float* __restrict__ w_hh3,
    const float* __restrict__ b_ih3, const float* __restrict__ b_hh3,
    const f16* __restrict__ w1h, const float* __restrict__ w1, const float* __restrict__ bd1,
    const float* __restrict__ w2, const float* __restrict__ bd2,
    const float* __restrict__ w3, const float* __restrict__ bd3,
    float* __restrict__ out)
{
    __shared__ __align__(16) unsigned char sm[SMEM_T];
    const int tid = threadIdx.x;
    const int Bb  = blockIdx.x * 16;  // 16 batch rows per block (all tile rows real)
    const int wv  = tid >> 6;         // wave 0..7
    const int l   = tid & 63;
    const int lc  = l & 15;           // col index within fragment
    const int lr  = l >> 4;           // k-group; owns tile rows 4lr..4lr+3

    // zero all LDS once (initial h state = 0)
    for (int e = tid * 4; e < SMEM_T; e += 512 * 4) *(float*)(sm + e) = 0.0f;
    // prologue: stage x(t=0) into X1 buf0 (16 rows x 3)
    if (tid < 48) {
        int row = tid / 3, c = tid - row * 3;
        *(float*)(sm + L_X1 + row * 16 + c * 4) = x[(size_t)(Bb + row) * T_SEQ * 3 + c];
    }

    // ---- persistent weight fragments in VGPRs ----
    f16x8 b1h[3][2];               // waves 0-3: w_hh1 [192][64]
    f16x8 b3x[3][4], b3h[3][2];    // waves 4-7: w_ih3 [192][128], w_hh3 [192][64]
    f16x8 b2x[3][2], b2h[3][4];    // all waves: w_ih2 [384][64], w_hh2 [384][128]
    float wi1[9];
    float bs1r = 0, bs1z = 0, bi1n = 0, bh1n = 0;
    float bs3r = 0, bs3z = 0, bi3n = 0, bh3n = 0;

    const int cj = (wv & 3) * 16 + lc;    // h-col for L1/L3 (and dense1 jo)
    if (wv < 4) {
        #pragma unroll
        for (int g = 0; g < 3; ++g)
            #pragma unroll
            for (int kt = 0; kt < 2; ++kt)
                b1h[g][kt] = loadB(w_hh1, g * 64 + cj, 64, kt * 32 + lr * 8);
        bs1r = b_ih1[cj] + b_hh1[cj];
        bs1z = b_ih1[cj + 64] + b_hh1[cj + 64];
        bi1n = b_ih1[cj + 128]; bh1n = b_hh1[cj + 128];
        #pragma unroll
        for (int g = 0; g < 3; ++g)
            #pragma unroll
            for (int i = 0; i < 3; ++i) wi1[g * 3 + i] = w_ih1[(cj + g * 64) * 3 + i];
    } else {
        #pragma unroll
        for (int g = 0; g < 3; ++g) {
            #pragma unroll
            for (int kt = 0; kt < 4; ++kt)
                b3x[g][kt] = loadB(w_ih3, g * 64 + cj, 128, kt * 32 + lr * 8);
            #pragma unroll
            for (int kt = 0; kt < 2; ++kt)
                b3h[g][kt] = loadB(w_hh3, g * 64 + cj, 64, kt * 32 + lr * 8);
        }
        bs3r = b_ih3[cj] + b_hh3[cj];
        bs3z = b_ih3[cj + 64] + b_hh3[cj + 64];
        bi3n = b_ih3[cj + 128]; bh3n = b_hh3[cj + 128];
    }
    const int cj2 = wv * 16 + lc;         // h-col for L2
    #pragma unroll
    for (int g = 0; g < 3; ++g) {
        #pragma unroll
        for (int kt = 0; kt < 2; ++kt)
            b2x[g][kt] = loadB(w_ih2, g * 128 + cj2, 64, kt * 32 + lr * 8);
        #pragma unroll
        for (int kt = 0; kt < 4; ++kt)
            b2h[g][kt] = loadB(w_hh2, g * 128 + cj2, 128, kt * 32 + lr * 8);
    }
    const float bs2r = b_ih2[cj2] + b_hh2[cj2];
    const float bs2z = b_ih2[cj2 + 128] + b_hh2[cj2 + 128];
    const float bi2n = b_ih2[cj2 + 256], bh2n = b_hh2[cj2 + 256];

    // recurrent state: 4 cells per thread (tile rows 4lr..4lr+3 -> 4 batch rows)
    float h1own[4] = {0, 0, 0, 0}, h2own[4] = {0, 0, 0, 0}, h3own[4] = {0, 0, 0, 0};
    f32x4 accd4 = {0, 0, 0, 0};          // dense1 acc (waves 0-3), all 4 rows real

    // w1-slice staging: thread -> (jo = tid>>3, chunk pre-swizzled)
    const int sjo = tid >> 3;
    const int skq = (tid & 7) ^ (sjo & 7);
    const size_t ssrc = (size_t)sjo * (T_SEQ * 64);

    __syncthreads();

    // Pipeline: iter t runs L1(t) | L2(t-1) | L3(t-2) | dense1(t-3), ONE barrier.
    #pragma unroll 1
    for (int t = 0; t <= T_SEQ + 2; ++t) {
        const int pe = t & 1, po = (t + 1) & 1;   // even/odd parity offsets

        // issue w1 slice load for step t-2 (written to LDS at iter end)
        f16x8 wstage;
        const int ts = t - 2;
        const bool doStage = (ts >= 0) && (ts < T_SEQ);
        if (doStage) {
            if constexpr (W1H) {
                wstage = *(const f16x8*)(w1h + ssrc + (size_t)ts * 64 + skq * 8);
            } else {
                const float* p = w1 + ssrc + (size_t)ts * 64 + skq * 8;
                float4 a = *(const float4*)p, b = *(const float4*)(p + 4);
                wstage[0] = (f16)a.x; wstage[1] = (f16)a.y; wstage[2] = (f16)a.z; wstage[3] = (f16)a.w;
                wstage[4] = (f16)b.x; wstage[5] = (f16)b.y; wstage[6] = (f16)b.z; wstage[7] = (f16)b.w;
            }
        }

        if (wv < 4) {
            if (t < T_SEQ) {   // ---- L1(t): read H1S[po], X1[pe]; write H1S/H1R[pe]
                f16x8 ah0 = ldsA(sm, L_H1S + po * 2048, 128, lc, lr * 16);
                f16x8 ah1 = ldsA(sm, L_H1S + po * 2048, 128, lc, 64 + lr * 16);
                f32x4 aR = {bs1r, bs1r, bs1r, bs1r};
                f32x4 aZ = {bs1z, bs1z, bs1z, bs1z};
                f32x4 aN = {bh1n, bh1n, bh1n, bh1n};
                __builtin_amdgcn_s_setprio(1);
                aR = mfma16(ah0, b1h[0][0], aR); aR = mfma16(ah1, b1h[0][1], aR);
                aZ = mfma16(ah0, b1h[1][0], aZ); aZ = mfma16(ah1, b1h[1][1], aZ);
                aN = mfma16(ah0, b1h[2][0], aN); aN = mfma16(ah1, b1h[2][1], aN);
                __builtin_amdgcn_s_setprio(0);
                #pragma unroll
                for (int ii = 0; ii < 4; ++ii) {
                    const int row = lr * 4 + ii;
                    float4 xv = *(const float4*)(sm + L_X1 + pe * 256 + row * 16);
                    float xgr = wi1[0] * xv.x + wi1[1] * xv.y + wi1[2] * xv.z;
                    float xgz = wi1[3] * xv.x + wi1[4] * xv.y + wi1[5] * xv.z;
                    float xgn = wi1[6] * xv.x + wi1[7] * xv.y + wi1[8] * xv.z;
                    h1own[ii] = gru_cell(aR[ii] + xgr, aZ[ii] + xgz, xgn + bi1n, aN[ii], h1own[ii]);
                    stH(sm, L_H1S + pe * 2048, 128, row, cj, (f16)h1own[ii]);
                    stH(sm, L_H1R + pe * 2048, 128, row, cj, (f16)fmaxf(h1own[ii], 0.f));
                }
            }
        } else {
            if (t >= 2 && t <= T_SEQ + 1) {   // ---- L3(t-2): read H2R[pe], H3S[po]; write H3S/H3R[pe]
                f16x8 ax0 = ldsA(sm, L_H2R + pe * 4096, 256, lc, lr * 16);
                f16x8 ax1 = ldsA(sm, L_H2R + pe * 4096, 256, lc, 64 + lr * 16);
                f16x8 ax2 = ldsA(sm, L_H2R + pe * 4096, 256, lc, 128 + lr * 16);
                f16x8 ax3 = ldsA(sm, L_H2R + pe * 4096, 256, lc, 192 + lr * 16);
                f16x8 ah0 = ldsA(sm, L_H3S + po * 2048, 128, lc, lr * 16);
                f16x8 ah1 = ldsA(sm, L_H3S + po * 2048, 128, lc, 64 + lr * 16);
                f32x4 aR  = {bs3r, bs3r, bs3r, bs3r};
                f32x4 aZ  = {bs3z, bs3z, bs3z, bs3z};
                f32x4 aXn = {bi3n, bi3n, bi3n, bi3n};
                f32x4 aHn = {bh3n, bh3n, bh3n, bh3n};
                __builtin_amdgcn_s_setprio(1);
                aR = mfma16(ax0, b3x[0][0], aR); aR = mfma16(ax1, b3x[0][1], aR);
                aR = mfma16(ax2, b3x[0][2], aR); aR = mfma16(ax3, b3x[0][3], aR);
                aR = mfma16(ah0, b3h[0][0], aR); aR = mfma16(ah1, b3h[0][1], aR);
                aZ = mfma16(ax0, b3x[1][0], aZ); aZ = mfma16(ax1, b3x[1][1], aZ);
                aZ = mfma16(ax2, b3x[1][2], aZ); aZ = mfma16(ax3, b3x[1][3], aZ);
                aZ = mfma16(ah0, b3h[1][0], aZ); aZ = mfma16(ah1, b3h[1][1], aZ);
                aXn = mfma16(ax0, b3x[2][0], aXn); aXn = mfma16(ax1, b3x[2][1], aXn);
                aXn = mfma16(ax2, b3x[2][2], aXn); aXn = mfma16(ax3, b3x[2][3], aXn);
                aHn = mfma16(ah0, b3h[2][0], aHn); aHn = mfma16(ah1, b3h[2][1], aHn);
                __builtin_amdgcn_s_setprio(0);
                #pragma unroll
                for (int ii = 0; ii < 4; ++ii) {
                    const int row = lr * 4 + ii;
                    h3own[ii] = gru_cell(aR[ii], aZ[ii], aXn[ii], aHn[ii], h3own[ii]);
                    stH(sm, L_H3S + pe * 2048, 128, row, cj, (f16)h3own[ii]);
                    stH(sm, L_H3R + pe * 2048, 128, row, cj, (f16)fmaxf(h3own[ii], 0.f));
                }
            }
        }

        if (t >= 1 && t <= T_SEQ) {   // ---- L2(t-1), all waves: read H1R[po], H2S[pe]; write H2S/H2R[po]
            f16x8 ax0 = ldsA(sm, L_H1R + po * 2048, 128, lc, lr * 16);
            f16x8 ax1 = ldsA(sm, L_H1R + po * 2048, 128, lc, 64 + lr * 16);
            f16x8 ah0 = ldsA(sm, L_H2S + pe * 4096, 256, lc, lr * 16);
            f16x8 ah1 = ldsA(sm, L_H2S + pe * 4096, 256, lc, 64 + lr * 16);
            f16x8 ah2 = ldsA(sm, L_H2S + pe * 4096, 256, lc, 128 + lr * 16);
            f16x8 ah3 = ldsA(sm, L_H2S + pe * 4096, 256, lc, 192 + lr * 16);
            f32x4 aR  = {bs2r, bs2r, bs2r, bs2r};
            f32x4 aZ  = {bs2z, bs2z, bs2z, bs2z};
            f32x4 aXn = {bi2n, bi2n, bi2n, bi2n};
            f32x4 aHn = {bh2n, bh2n, bh2n, bh2n};
            __builtin_amdgcn_s_setprio(1);
            aR = mfma16(ax0, b2x[0][0], aR); aR = mfma16(ax1, b2x[0][1], aR);
            aR = mfma16(ah0, b2h[0][0], aR); aR = mfma16(ah1, b2h[0][1], aR);
            aR = mfma16(ah2, b2h[0][2], aR); aR = mfma16(ah3, b2h[0][3], aR);
            aZ = mfma16(ax0, b2x[1][0], aZ); aZ = mfma16(ax1, b2x[1][1], aZ);
            aZ = mfma16(ah0, b2h[1][0], aZ); aZ = mfma16(ah1, b2h[1][1], aZ);
            aZ = mfma16(ah2, b2h[1][2], aZ); aZ = mfma16(ah3, b2h[1][3], aZ);
            aXn = mfma16(ax0, b2x[2][0], aXn); aXn = mfma16(ax1, b2x[2][1], aXn);
            aHn = mfma16(ah0, b2h[2][0], aHn); aHn = mfma16(ah1, b2h[2][1], aHn);
            aHn = mfma16(ah2, b2h[2][2], aHn); aHn = mfma16(ah3, b2h[2][3], aHn);
            __builtin_amdgcn_s_setprio(0);
            #pragma unroll
            for (int ii = 0; ii < 4; ++ii) {
                const int row = lr * 4 + ii;
                h2own[ii] = gru_cell(aR[ii], aZ[ii], aXn[ii], aHn[ii], h2own[ii]);
                stH(sm, L_H2S + po * 4096, 256, row, cj2, (f16)h2own[ii]);
                stH(sm, L_H2R + po * 4096, 256, row, cj2, (f16)fmaxf(h2own[ii], 0.f));
            }
        }

        if (wv < 4 && t >= 3) {   // ---- dense1(t-3): read H3R[po], W1D[po]
            f16x8 dh0 = ldsA(sm, L_H3R + po * 2048, 128, lc, lr * 16);
            f16x8 dh1 = ldsA(sm, L_H3R + po * 2048, 128, lc, 64 + lr * 16);
            const unsigned char* wb = sm + L_W1D + po * 8192 + cj * 128;
            f16x8 wb0 = *(const f16x8*)(wb + ((lr ^ (cj & 7)) << 4));
            f16x8 wb1 = *(const f16x8*)(wb + (((4 + lr) ^ (cj & 7)) << 4));
            accd4 = mfma16(dh0, wb0, accd4);
            accd4 = mfma16(dh1, wb1, accd4);
        }

        // late writes: w1 slice (parity ts&1 == pe), x(t+1) into X1[po]
        if (doStage)
            *(f16x8*)(sm + L_W1D + pe * 8192 + tid * 16) = wstage;
        if (wv >= 4 && t + 1 < T_SEQ && tid < 256 + 48) {
            int h = tid - 256, row = h / 3, c = h - row * 3;
            *(float*)(sm + L_X1 + po * 256 + row * 16 + c * 4) =
                x[(size_t)(Bb + row) * T_SEQ * 3 + (size_t)(t + 1) * 3 + c];
        }
        __syncthreads();
    }

    // ---------- head: dense1 bias+relu -> dense2 -> dense3 ----------
    float* o1 = (float*)sm;              // [16][68]
    if (wv < 4) {
        #pragma unroll
        for (int ii = 0; ii < 4; ++ii) {
            const int row = lr * 4 + ii;          // tile row == batch row
            o1[row * 68 + cj] = fmaxf(accd4[ii] + bd1[cj], 0.f);
        }
    }
    __syncthreads();
    float* o2 = (float*)(sm + 8192);     // [16][36]
    {
        const int bb = tid & 15, m = tid >> 4;    // 16 rows x 32 cols = 512 outputs
        float acc = bd2[m];
        const float* w2p = w2 + m * 64;
        const float* o1q = o1 + bb * 68;
        #pragma unroll
        for (int i = 0; i < 16; ++i) {
            float4 a = *(const float4*)(o1q + i * 4);
            float4 wv8 = *(const float4*)(w2p + i * 4);
            acc += a.x * wv8.x + a.y * wv8.y + a.z * wv8.z + a.w * wv8.w;
        }
        o2[bb * 36 + m] = fmaxf(acc, 0.f);
    }
    __syncthreads();
    for (int e = tid; e < 16 * 250; e += 512) {
        const int bb = e / 250, p = e - bb * 250;
        float acc = bd3[p];
        const float* w3p = w3 + p * 32;
        const float* o2p = o2 + bb * 36;
        #pragma unroll
        for (int i = 0; i < 8; ++i) {
            float4 a = *(const float4*)(o2p + i * 4);
            float4 wv8 = *(const float4*)(w3p + i * 4);
            acc += a.x * wv8.x + a.y * wv8.y + a.z * wv8.z + a.w * wv8.w;
        }
        out[(size_t)(Bb + bb) * 250 + p] = fmaxf(acc, 0.f);
    }
}

extern "C" void kernel_launch(void* const* d_in, const int* in_sizes, int n_in,
                              void* d_out, int out_size, void* d_ws, size_t ws_size,
                              hipStream_t stream) {
    const float* x     = (const float*)d_in[0];
    const float* w_ih1 = (const float*)d_in[1];
    const float* w_hh1 = (const float*)d_in[2];
    const float* b_ih1 = (const float*)d_in[3];
    const float* b_hh1 = (const float*)d_in[4];
    const float* w_ih2 = (const float*)d_in[5];
    const float* w_hh2 = (const float*)d_in[6];
    const float* b_ih2 = (const float*)d_in[7];
    const float* b_hh2 = (const float*)d_in[8];
    const float* w_ih3 = (const float*)d_in[9];
    const float* w_hh3 = (const float*)d_in[10];
    const float* b_ih3 = (const float*)d_in[11];
    const float* b_hh3 = (const float*)d_in[12];
    const float* w1    = (const float*)d_in[13];
    const float* bd1   = (const float*)d_in[14];
    const float* w2    = (const float*)d_in[15];
    const float* bd2   = (const float*)d_in[16];
    const float* w3    = (const float*)d_in[17];
    const float* bd3   = (const float*)d_in[18];
    float* out = (float*)d_out;

    const int n1 = 64 * T_SEQ * 64;                 // w1 elements
    const bool useF16 = ws_size >= (size_t)n1 * sizeof(f16);
    f16* w1h = (f16*)d_ws;

    if (useF16) {
        hipLaunchKernelGGL(cvt_f16, dim3((n1 + 255) / 256), dim3(256), 0, stream, w1, w1h, n1);
        hipLaunchKernelGGL((gru_fused<true>), dim3(B_TOT / 16), dim3(512), 0, stream,
                           x, w_ih1, w_hh1, b_ih1, b_hh1, w_ih2, w_hh2, b_ih2, b_hh2,
                           w_ih3, w_hh3, b_ih3, b_hh3,
                           w1h, w1, bd1, w2, bd2, w3, bd3, out);
    } else {
        hipLaunchKernelGGL((gru_fused<false>), dim3(B_TOT / 16), dim3(512), 0, stream,
                           x, w_ih1, w_hh1, b_ih1, b_hh1, w_ih2, w_hh2, b_ih2, b_hh2,
                           w_ih3, w_hh3, b_ih3, b_hh3,
                           w1h, w1, bd1, w2, bd2, w3, bd3, out);
    }
}

// Round 16
// 1347.352 us; speedup vs baseline: 1.2669x; 1.2669x over previous
//
#include <hip/hip_runtime.h>

#define T_SEQ 543
#define B_TOT 2048

typedef _Float16 f16;
typedef f16   f16x8 __attribute__((ext_vector_type(8)));
typedef float f32x4 __attribute__((ext_vector_type(4)));

#if defined(__has_builtin)
#if __has_builtin(__builtin_amdgcn_rcpf)
#define RCP(x) __builtin_amdgcn_rcpf(x)
#endif
#endif
#ifndef RCP
#define RCP(x) (1.0f / (x))
#endif

__device__ __forceinline__ float sigm(float x)   { return RCP(1.0f + __expf(-x)); }
__device__ __forceinline__ float tanh_f(float x) { return fmaf(-2.0f, RCP(__expf(2.0f * x) + 1.0f), 1.0f); }

__device__ __forceinline__ f32x4 mfma16(f16x8 a, f16x8 b, f32x4 c) {
    return __builtin_amdgcn_mfma_f32_16x16x32_f16(a, b, c, 0, 0, 0);
}

// B-fragment: lane holds w[nrow][k0..k0+8) as f16x8 (row-major fp32 source)
__device__ __forceinline__ f16x8 loadB(const float* __restrict__ g, int nrow, int ldk, int k0) {
    const float* p = g + (size_t)nrow * ldk + k0;
    float4 a = *(const float4*)p;
    float4 b = *(const float4*)(p + 4);
    f16x8 r;
    r[0] = (f16)a.x; r[1] = (f16)a.y; r[2] = (f16)a.z; r[3] = (f16)a.w;
    r[4] = (f16)b.x; r[5] = (f16)b.y; r[6] = (f16)b.z; r[7] = (f16)b.w;
    return r;
}

// ---- LDS layout (bytes). Batch row r -> tile row 2r; odd rows stay 0.
// ALL state buffers double-buffered (single barrier per iteration).
#define L_H1S 0        // 2 x [16][64]  f16 = 4096  (raw h1)
#define L_H1R 4096     // 2 x [16][64]  f16 = 4096  (relu h1)
#define L_H2S 8192     // 2 x [16][128] f16 = 8192  (raw h2)
#define L_H2R 16384    // 2 x [16][128] f16 = 8192  (relu h2)
#define L_H3S 24576    // 2 x [16][64]  f16 = 4096  (raw h3)
#define L_H3R 28672    // 2 x [16][64]  f16 = 4096  (relu h3)
#define L_X1  32768    // 2 x [16]x16B      = 512   (x staged)
#define L_W1D 33280    // 2 x 8KB           = 16384 (w1 t-slice [64 jo][64 k] f16)
#define SMEM_T 49664

// XOR-swizzled LDS accessors (spread row-strided b128 reads over banks)
__device__ __forceinline__ f16x8 ldsA(const unsigned char* sm, int base, int stride, int row, int kByte) {
    int off = (base + row * stride + kByte) ^ ((row & 7) << 4);
    return *(const f16x8*)(sm + off);
}
__device__ __forceinline__ void stH(unsigned char* sm, int base, int stride, int row, int col, f16 v) {
    int off = (base + row * stride + col * 2) ^ ((row & 7) << 4);
    *(f16*)(sm + off) = v;
}

__global__ void cvt_f16(const float* __restrict__ s, f16* __restrict__ d, int n) {
    int i = blockIdx.x * 256 + threadIdx.x;
    if (i < n) d[i] = (f16)s[i];
}

__device__ __forceinline__ float gru_cell(float aR, float aZ, float aXn, float aHn, float hprev) {
    float r = sigm(aR);
    float z = sigm(aZ);
    float n = tanh_f(aXn + r * aHn);
    return fmaf(z, hprev - n, n);
}

template<bool W1H>
__global__ __launch_bounds__(512, 2) void gru_fused(
    const float* __restrict__ x,
    const float* __restrict__ w_ih1, const float* __restrict__ w_hh1,
    const float* __restrict__ b_ih1, const float* __restrict__ b_hh1,
    const float* __restrict__ w_ih2, const float* __restrict__ w_hh2,
    const float* __restrict__ b_ih2, const float* __restrict__ b_hh2,
    const float* __restrict__ w_ih3, const float* __restrict__ w_hh3,
    const float* __restrict__ b_ih3, const float* __restrict__ b_hh3,
    const f16* __restrict__ w1h, const float* __restrict__ w1, const float* __restrict__ bd1,
    const float* __restrict__ w2, const float* __restrict__ bd2,
    const float* __restrict__ w3, const float* __restrict__ bd3,
    float* __restrict__ out)
{
    __shared__ __align__(16) unsigned char sm[SMEM_T];
    const int tid = threadIdx.x;
    const int Bb  = blockIdx.x * 8;   // 8 batch rows per block
    const int wv  = tid >> 6;         // wave 0..7
    const int l   = tid & 63;
    const int lc  = l & 15;           // col index within fragment
    const int lr  = l >> 4;           // k-group; owns tile rows 4lr, 4lr+2

    // zero all LDS once (odd/pad rows must stay zero forever)
    for (int e = tid * 4; e < SMEM_T; e += 512 * 4) *(float*)(sm + e) = 0.0f;
    // prologue: stage x(t=0) into X1 buf0
    if (tid < 24) {
        int row = tid / 3, c = tid - row * 3;
        *(float*)(sm + L_X1 + row * 32 + c * 4) = x[(size_t)(Bb + row) * T_SEQ * 3 + c];
    }

    // ---- persistent weight fragments in VGPRs (same as round 11) ----
    f16x8 b1h[3][2];               // waves 0-3: w_hh1 [192][64]
    f16x8 b3x[3][4], b3h[3][2];    // waves 4-7: w_ih3 [192][128], w_hh3 [192][64]
    f16x8 b2x[3][2], b2h[3][4];    // all waves: w_ih2 [384][64], w_hh2 [384][128]
    float wi1[9];
    float bs1r = 0, bs1z = 0, bi1n = 0, bh1n = 0;
    float bs3r = 0, bs3z = 0, bi3n = 0, bh3n = 0;

    const int cj = (wv & 3) * 16 + lc;    // h-col for L1/L3 (and dense1 jo)
    if (wv < 4) {
        #pragma unroll
        for (int g = 0; g < 3; ++g)
            #pragma unroll
            for (int kt = 0; kt < 2; ++kt)
                b1h[g][kt] = loadB(w_hh1, g * 64 + cj, 64, kt * 32 + lr * 8);
        bs1r = b_ih1[cj] + b_hh1[cj];
        bs1z = b_ih1[cj + 64] + b_hh1[cj + 64];
        bi1n = b_ih1[cj + 128]; bh1n = b_hh1[cj + 128];
        #pragma unroll
        for (int g = 0; g < 3; ++g)
            #pragma unroll
            for (int i = 0; i < 3; ++i) wi1[g * 3 + i] = w_ih1[(cj + g * 64) * 3 + i];
    } else {
        #pragma unroll
        for (int g = 0; g < 3; ++g) {
            #pragma unroll
            for (int kt = 0; kt < 4; ++kt)
                b3x[g][kt] = loadB(w_ih3, g * 64 + cj, 128, kt * 32 + lr * 8);
            #pragma unroll
            for (int kt = 0; kt < 2; ++kt)
                b3h[g][kt] = loadB(w_hh3, g * 64 + cj, 64, kt * 32 + lr * 8);
        }
        bs3r = b_ih3[cj] + b_hh3[cj];
        bs3z = b_ih3[cj + 64] + b_hh3[cj + 64];
        bi3n = b_ih3[cj + 128]; bh3n = b_hh3[cj + 128];
    }
    const int cj2 = wv * 16 + lc;         // h-col for L2
    #pragma unroll
    for (int g = 0; g < 3; ++g) {
        #pragma unroll
        for (int kt = 0; kt < 2; ++kt)
            b2x[g][kt] = loadB(w_ih2, g * 128 + cj2, 64, kt * 32 + lr * 8);
        #pragma unroll
        for (int kt = 0; kt < 4; ++kt)
            b2h[g][kt] = loadB(w_hh2, g * 128 + cj2, 128, kt * 32 + lr * 8);
    }
    const float bs2r = b_ih2[cj2] + b_hh2[cj2];
    const float bs2z = b_ih2[cj2 + 128] + b_hh2[cj2 + 128];
    const float bi2n = b_ih2[cj2 + 256], bh2n = b_hh2[cj2 + 256];

    // recurrent state: 2 cells per thread (tile rows 4lr, 4lr+2)
    float h1own[2] = {0, 0}, h2own[2] = {0, 0}, h3own[2] = {0, 0};
    f32x4 accd4 = {0, 0, 0, 0};          // dense1 acc (waves 0-3)

    // w1-slice staging: thread -> (jo = tid>>3, chunk pre-swizzled)
    const int sjo = tid >> 3;
    const int skq = (tid & 7) ^ (sjo & 7);
    const size_t ssrc = (size_t)sjo * (T_SEQ * 64);

    __syncthreads();

    // Pipeline: iter t runs L1(t) | L2(t-1) | L3(t-2) | dense1(t-3), ONE barrier.
    #pragma unroll 1
    for (int t = 0; t <= T_SEQ + 2; ++t) {
        const int pe = t & 1, po = (t + 1) & 1;   // even/odd parity offsets

        // issue w1 slice load for step t-2 (written to LDS at iter end)
        f16x8 wstage;
        const int ts = t - 2;
        const bool doStage = (ts >= 0) && (ts < T_SEQ);
        if (doStage) {
            if constexpr (W1H) {
                wstage = *(const f16x8*)(w1h + ssrc + (size_t)ts * 64 + skq * 8);
            } else {
                const float* p = w1 + ssrc + (size_t)ts * 64 + skq * 8;
                float4 a = *(const float4*)p, b = *(const float4*)(p + 4);
                wstage[0] = (f16)a.x; wstage[1] = (f16)a.y; wstage[2] = (f16)a.z; wstage[3] = (f16)a.w;
                wstage[4] = (f16)b.x; wstage[5] = (f16)b.y; wstage[6] = (f16)b.z; wstage[7] = (f16)b.w;
            }
        }

        if (wv < 4) {
            if (t < T_SEQ) {   // ---- L1(t): read H1S[po], X1[pe]; write H1S/H1R[pe]
                f16x8 ah0 = ldsA(sm, L_H1S + po * 2048, 128, lc, lr * 16);
                f16x8 ah1 = ldsA(sm, L_H1S + po * 2048, 128, lc, 64 + lr * 16);
                f32x4 aR = {bs1r, bs1r, bs1r, bs1r};
                f32x4 aZ = {bs1z, bs1z, bs1z, bs1z};
                f32x4 aN = {bh1n, bh1n, bh1n, bh1n};
                __builtin_amdgcn_s_setprio(1);
                aR = mfma16(ah0, b1h[0][0], aR); aR = mfma16(ah1, b1h[0][1], aR);
                aZ = mfma16(ah0, b1h[1][0], aZ); aZ = mfma16(ah1, b1h[1][1], aZ);
                aN = mfma16(ah0, b1h[2][0], aN); aN = mfma16(ah1, b1h[2][1], aN);
                __builtin_amdgcn_s_setprio(0);
                #pragma unroll
                for (int ii = 0; ii < 2; ++ii) {
                    const int i = ii * 2, row = lr * 4 + i;
                    float4 xv = *(const float4*)(sm + L_X1 + pe * 256 + row * 16);
                    float xgr = wi1[0] * xv.x + wi1[1] * xv.y + wi1[2] * xv.z;
                    float xgz = wi1[3] * xv.x + wi1[4] * xv.y + wi1[5] * xv.z;
                    float xgn = wi1[6] * xv.x + wi1[7] * xv.y + wi1[8] * xv.z;
                    h1own[ii] = gru_cell(aR[i] + xgr, aZ[i] + xgz, xgn + bi1n, aN[i], h1own[ii]);
                    stH(sm, L_H1S + pe * 2048, 128, row, cj, (f16)h1own[ii]);
                    stH(sm, L_H1R + pe * 2048, 128, row, cj, (f16)fmaxf(h1own[ii], 0.f));
                }
            }
        } else {
            if (t >= 2 && t <= T_SEQ + 1) {   // ---- L3(t-2): read H2R[pe], H3S[po]; write H3S/H3R[pe]
                f16x8 ax0 = ldsA(sm, L_H2R + pe * 4096, 256, lc, lr * 16);
                f16x8 ax1 = ldsA(sm, L_H2R + pe * 4096, 256, lc, 64 + lr * 16);
                f16x8 ax2 = ldsA(sm, L_H2R + pe * 4096, 256, lc, 128 + lr * 16);
                f16x8 ax3 = ldsA(sm, L_H2R + pe * 4096, 256, lc, 192 + lr * 16);
                f16x8 ah0 = ldsA(sm, L_H3S + po * 2048, 128, lc, lr * 16);
                f16x8 ah1 = ldsA(sm, L_H3S + po * 2048, 128, lc, 64 + lr * 16);
                f32x4 aR  = {bs3r, bs3r, bs3r, bs3r};
                f32x4 aZ  = {bs3z, bs3z, bs3z, bs3z};
                f32x4 aXn = {bi3n, bi3n, bi3n, bi3n};
                f32x4 aHn = {bh3n, bh3n, bh3n, bh3n};
                __builtin_amdgcn_s_setprio(1);
                aR = mfma16(ax0, b3x[0][0], aR); aR = mfma16(ax1, b3x[0][1], aR);
                aR = mfma16(ax2, b3x[0][2], aR); aR = mfma16(ax3, b3x[0][3], aR);
                aR = mfma16(ah0, b3h[0][0], aR); aR = mfma16(ah1, b3h[0][1], aR);
                aZ = mfma16(ax0, b3x[1][0], aZ); aZ = mfma16(ax1, b3x[1][1], aZ);
                aZ = mfma16(ax2, b3x[1][2], aZ); aZ = mfma16(ax3, b3x[1][3], aZ);
                aZ = mfma16(ah0, b3h[1][0], aZ); aZ = mfma16(ah1, b3h[1][1], aZ);
                aXn = mfma16(ax0, b3x[2][0], aXn); aXn = mfma16(ax1, b3x[2][1], aXn);
                aXn = mfma16(ax2, b3x[2][2], aXn); aXn = mfma16(ax3, b3x[2][3], aXn);
                aHn = mfma16(ah0, b3h[2][0], aHn); aHn = mfma16(ah1, b3h[2][1], aHn);
                __builtin_amdgcn_s_setprio(0);
                #pragma unroll
                for (int ii = 0; ii < 2; ++ii) {
                    const int i = ii * 2, row = lr * 4 + i;
                    h3own[ii] = gru_cell(aR[i], aZ[i], aXn[i], aHn[i], h3own[ii]);
                    stH(sm, L_H3S + pe * 2048, 128, row, cj, (f16)h3own[ii]);
                    stH(sm, L_H3R + pe * 2048, 128, row, cj, (f16)fmaxf(h3own[ii], 0.f));
                }
            }
        }

        if (t >= 1 && t <= T_SEQ) {   // ---- L2(t-1), all waves: read H1R[po], H2S[pe]; write H2S/H2R[po]
            f16x8 ax0 = ldsA(sm, L_H1R + po * 2048, 128, lc, lr * 16);
            f16x8 ax1 = ldsA(sm, L_H1R + po * 2048, 128, lc, 64 + lr * 16);
            f16x8 ah0 = ldsA(sm, L_H2S + pe * 4096, 256, lc, lr * 16);
            f16x8 ah1 = ldsA(sm, L_H2S + pe * 4096, 256, lc, 64 + lr * 16);
            f16x8 ah2 = ldsA(sm, L_H2S + pe * 4096, 256, lc, 128 + lr * 16);
            f16x8 ah3 = ldsA(sm, L_H2S + pe * 4096, 256, lc, 192 + lr * 16);
            f32x4 aR  = {bs2r, bs2r, bs2r, bs2r};
            f32x4 aZ  = {bs2z, bs2z, bs2z, bs2z};
            f32x4 aXn = {bi2n, bi2n, bi2n, bi2n};
            f32x4 aHn = {bh2n, bh2n, bh2n, bh2n};
            __builtin_amdgcn_s_setprio(1);
            aR = mfma16(ax0, b2x[0][0], aR); aR = mfma16(ax1, b2x[0][1], aR);
            aR = mfma16(ah0, b2h[0][0], aR); aR = mfma16(ah1, b2h[0][1], aR);
            aR = mfma16(ah2, b2h[0][2], aR); aR = mfma16(ah3, b2h[0][3], aR);
            aZ = mfma16(ax0, b2x[1][0], aZ); aZ = mfma16(ax1, b2x[1][1], aZ);
            aZ = mfma16(ah0, b2h[1][0], aZ); aZ = mfma16(ah1, b2h[1][1], aZ);
            aZ = mfma16(ah2, b2h[1][2], aZ); aZ = mfma16(ah3, b2h[1][3], aZ);
            aXn = mfma16(ax0, b2x[2][0], aXn); aXn = mfma16(ax1, b2x[2][1], aXn);
            aHn = mfma16(ah0, b2h[2][0], aHn); aHn = mfma16(ah1, b2h[2][1], aHn);
            aHn = mfma16(ah2, b2h[2][2], aHn); aHn = mfma16(ah3, b2h[2][3], aHn);
            __builtin_amdgcn_s_setprio(0);
            #pragma unroll
            for (int ii = 0; ii < 2; ++ii) {
                const int i = ii * 2, row = lr * 4 + i;
                h2own[ii] = gru_cell(aR[i], aZ[i], aXn[i], aHn[i], h2own[ii]);
                stH(sm, L_H2S + po * 4096, 256, row, cj2, (f16)h2own[ii]);
                stH(sm, L_H2R + po * 4096, 256, row, cj2, (f16)fmaxf(h2own[ii], 0.f));
            }
        }

        if (wv < 4 && t >= 3) {   // ---- dense1(t-3): read H3R[po], W1D[po]
            f16x8 dh0 = ldsA(sm, L_H3R + po * 2048, 128, lc, lr * 16);
            f16x8 dh1 = ldsA(sm, L_H3R + po * 2048, 128, lc, 64 + lr * 16);
            const unsigned char* wb = sm + L_W1D + po * 8192 + cj * 128;
            f16x8 wb0 = *(const f16x8*)(wb + ((lr ^ (cj & 7)) << 4));
            f16x8 wb1 = *(const f16x8*)(wb + (((4 + lr) ^ (cj & 7)) << 4));
            accd4 = mfma16(dh0, wb0, accd4);
            accd4 = mfma16(dh1, wb1, accd4);
        }

        // late writes: w1 slice (parity ts&1 == pe), x(t+1) into X1[po]
        if (doStage)
            *(f16x8*)(sm + L_W1D + pe * 8192 + tid * 16) = wstage;
        if (wv >= 4 && t + 1 < T_SEQ && tid < 256 + 24) {
            int h = tid - 256, row = h / 3, c = h - row * 3;
            *(float*)(sm + L_X1 + po * 256 + row * 32 + c * 4) =
                x[(size_t)(Bb + row) * T_SEQ * 3 + (size_t)(t + 1) * 3 + c];
        }
        __syncthreads();
    }

    // ---------- head: dense1 bias+relu -> dense2 -> dense3 ----------
    float* o1 = (float*)sm;              // [8][68]
    if (wv < 4) {
        #pragma unroll
        for (int ii = 0; ii < 2; ++ii) {
            const int row = lr * 4 + ii * 2;
            o1[(row >> 1) * 68 + cj] = fmaxf(accd4[ii * 2] + bd1[cj], 0.f);
        }
    }
    __syncthreads();
    float* o2 = (float*)(sm + 4096);     // [8][36]
    if (tid < 256) {
        const int bb = tid & 7, m = tid >> 3;
        float acc = bd2[m];
        const float* w2p = w2 + m * 64;
        const float* o1q = o1 + bb * 68;
        #pragma unroll
        for (int i = 0; i < 16; ++i) {
            float4 a = *(const float4*)(o1q + i * 4);
            float4 wv8 = *(const float4*)(w2p + i * 4);
            acc += a.x * wv8.x + a.y * wv8.y + a.z * wv8.z + a.w * wv8.w;
        }
        o2[bb * 36 + m] = fmaxf(acc, 0.f);
    }
    __syncthreads();
    for (int e = tid; e < 8 * 250; e += 512) {
        const int bb = e / 250, p = e - bb * 250;
        float acc = bd3[p];
        const float* w3p = w3 + p * 32;
        const float* o2p = o2 + bb * 36;
        #pragma unroll
        for (int i = 0; i < 8; ++i) {
            float4 a = *(const float4*)(o2p + i * 4);
            float4 wv8 = *(const float4*)(w3p + i * 4);
            acc += a.x * wv8.x + a.y * wv8.y + a.z * wv8.z + a.w * wv8.w;
        }
        out[(size_t)(Bb + bb) * 250 + p] = fmaxf(acc, 0.f);
    }
}

extern "C" void kernel_launch(void* const* d_in, const int* in_sizes, int n_in,
                              void* d_out, int out_size, void* d_ws, size_t ws_size,
                              hipStream_t stream) {
    const float* x     = (const float*)d_in[0];
    const float* w_ih1 = (const float*)d_in[1];
    const float* w_hh1 = (const float*)d_in[2];
    const float* b_ih1 = (const float*)d_in[3];
    const float* b_hh1 = (const float*)d_in[4];
    const float* w_ih2 = (const float*)d_in[5];
    const float* w_hh2 = (const float*)d_in[6];
    const float* b_ih2 = (const float*)d_in[7];
    const float* b_hh2 = (const float*)d_in[8];
    const float* w_ih3 = (const float*)d_in[9];
    const float* w_hh3 = (const float*)d_in[10];
    const float* b_ih3 = (const float*)d_in[11];
    const float* b_hh3 = (const float*)d_in[12];
    const float* w1    = (const float*)d_in[13];
    const float* bd1   = (const float*)d_in[14];
    const float* w2    = (const float*)d_in[15];
    const float* bd2   = (const float*)d_in[16];
    const float* w3    = (const float*)d_in[17];
    const float* bd3   = (const float*)d_in[18];
    float* out = (float*)d_out;

    const int n1 = 64 * T_SEQ * 64;                 // w1 elements
    const bool useF16 = ws_size >= (size_t)n1 * sizeof(f16);
    f16* w1h = (f16*)d_ws;

    if (useF16) {
        hipLaunchKernelGGL(cvt_f16, dim3((n1 + 255) / 256), dim3(256), 0, stream, w1, w1h, n1);
        hipLaunchKernelGGL((gru_fused<true>), dim3(B_TOT / 8), dim3(512), 0, stream,
                           x, w_ih1, w_hh1, b_ih1, b_hh1, w_ih2, w_hh2, b_ih2, b_hh2,
                           w_ih3, w_hh3, b_ih3, b_hh3,
                           w1h, w1, bd1, w2, bd2, w3, bd3, out);
    } else {
        hipLaunchKernelGGL((gru_fused<false>), dim3(B_TOT / 8), dim3(512), 0, stream,
                           x, w_ih1, w_hh1, b_ih1, b_hh1, w_ih2, w_hh2, b_ih2, b_hh2,
                           w_ih3, w_hh3, b_ih3, b_hh3,
                           w1h, w1, bd1, w2, bd2, w3, bd3, out);
    }
}